// Round 3
// baseline (5915.435 us; speedup 1.0000x reference)
//
#include <hip/hip_runtime.h>
#include <hip/hip_bf16.h>

#define BB 64
#define EE 512
#define HH 1024
#define KK 1536
#define VV 50257
#define SS 512

#define NWG1 64            // GEMM1: mi = bid&3 (4), ni = bid>>2 (16): 16M x 64N
#define NWG2 32            // GEMM2: mi = rb&3 (4),  ni = rb>>2 (8):  16M x 64N
#define NWG (NWG1 + NWG2)  // 96 blocks
#define GRP 24             // blocks per mi-group (16 GEMM1 + 8 GEMM2)

typedef __bf16 bf16x8 __attribute__((ext_vector_type(8)));
typedef float f32x4 __attribute__((ext_vector_type(4)));

__device__ __forceinline__ bf16x8 load_bf8(const __bf16* p) {
    return *reinterpret_cast<const bf16x8*>(p);
}

__device__ __forceinline__ bf16x8 cvt8(const float* p) {
    f32x4 a = *reinterpret_cast<const f32x4*>(p);
    f32x4 b = *reinterpret_cast<const f32x4*>(p + 4);
    bf16x8 r;
    r[0] = (__bf16)a[0]; r[1] = (__bf16)a[1]; r[2] = (__bf16)a[2]; r[3] = (__bf16)a[3];
    r[4] = (__bf16)b[0]; r[5] = (__bf16)b[1]; r[6] = (__bf16)b[2]; r[7] = (__bf16)b[3];
    return r;
}

// Hand-rolled inter-block barrier with explicit agent-scope release/acquire.
// Monotonic target; counter zeroed at the start of every kernel_launch.
__device__ __forceinline__ void group_barrier(unsigned* ctr, unsigned target) {
    __syncthreads();
    if (threadIdx.x == 0) {
        __threadfence();  // release: drain stores, write back L2
        __hip_atomic_fetch_add(ctr, 1u, __ATOMIC_RELEASE, __HIP_MEMORY_SCOPE_AGENT);
        while (__hip_atomic_load(ctr, __ATOMIC_ACQUIRE, __HIP_MEMORY_SCOPE_AGENT) < target) {
            __builtin_amdgcn_s_sleep(1);
        }
        __threadfence();  // acquire: invalidate L1/L2 so data reads are fresh
    }
    __syncthreads();
}

// Decode sequence tokens to int32 (auto-detect int64 vs int32) + zero barriers.
__global__ void tokens_kernel(const void* __restrict__ seq, int* __restrict__ tok,
                              unsigned* __restrict__ bar) {
    if (blockIdx.x == 0 && threadIdx.x < 4)
        __hip_atomic_store(&bar[threadIdx.x * 32], 0u, __ATOMIC_RELEASE,
                           __HIP_MEMORY_SCOPE_AGENT);
    const unsigned* u = (const unsigned*)seq;
    bool is64 = true;
    #pragma unroll 1
    for (int i = 0; i < 64; ++i) {
        if (u[2 * i + 1] != 0u) { is64 = false; break; }
    }
    int i = blockIdx.x * 256 + threadIdx.x;
    if (i < BB * SS) tok[i] = is64 ? (int)u[2 * i] : (int)u[i];
}

// fp32 [R][C] row-major -> bf16 [C][R]
__global__ __launch_bounds__(256) void transpose_kernel(
    const float* __restrict__ in, __bf16* __restrict__ out, int R, int C) {
    __shared__ float t[32][33];
    int bc = C >> 5;
    int br = blockIdx.x / bc;
    int bco = blockIdx.x % bc;
    int R0 = br << 5, C0 = bco << 5;
    int c = threadIdx.x & 31, r0 = threadIdx.x >> 5;
    #pragma unroll
    for (int i = 0; i < 4; ++i) {
        int r = r0 + i * 8;
        t[r][c] = in[(size_t)(R0 + r) * C + C0 + c];
    }
    __syncthreads();
    #pragma unroll
    for (int i = 0; i < 4; ++i) {
        int r = r0 + i * 8;
        out[(size_t)(C0 + r) * R + R0 + c] = (__bf16)t[c][r];
    }
}

__global__ void init_kernel(const float* __restrict__ h1, const float* __restrict__ h2,
                            __bf16* __restrict__ h1bf, __bf16* __restrict__ h2bf) {
    int i = blockIdx.x * 256 + threadIdx.x;
    if (i < BB * HH) h1bf[i] = (__bf16)h1[i];
    if (i < BB * EE) h2bf[i] = (__bf16)h2[i];
}

// Persistent recurrent kernel. 513 pipelined iterations.
// Iter i: GEMM1 (blocks [0,64))  computes h1_{i+1} = tanh([e_i, h1_i] W1)  (i<512)
//         GEMM2 (blocks [64,96)) computes h2_i     = tanh([h1_i, h2_{i-1}] W2) (i>=1)
// Sync: 4 independent 24-block mi-groups (rows decouple across mi), hand-rolled
// barrier. Weights in VGPRs (48 bf16x8/wave), tokens in LDS, bias in registers.
__global__ __launch_bounds__(256, 1) void rnn_persist(
    const int* __restrict__ tok32, const float* __restrict__ embW,
    const float* __restrict__ b1, const float* __restrict__ b2,
    const __bf16* __restrict__ W1t, const __bf16* __restrict__ W2t,
    __bf16* __restrict__ h1a, __bf16* __restrict__ h1b,
    __bf16* __restrict__ h2a, __bf16* __restrict__ h2b,
    float* __restrict__ h1out, float* __restrict__ h2out,
    unsigned* __restrict__ bar) {
    const int bid = blockIdx.x;
    const bool is1 = bid < NWG1;
    const int rb = is1 ? bid : bid - NWG1;
    const int mi = rb & 3;
    const int ni = rb >> 2;
    const int m0 = mi << 4;
    const int n0 = ni << 6;
    const int N = is1 ? HH : EE;
    const int tid = threadIdx.x;
    const int w = tid >> 6;
    const int l = tid & 63;
    const int l16 = l & 15;
    const int kg = l >> 4;
    unsigned* ctr = bar + mi * 32;  // 128B-separated per-group counters

    __shared__ int tok_s[SS][16];
    __shared__ float red[4][16][66];

    if (is1) {
        for (int idx = tid; idx < SS * 16; idx += 256) {
            int t = idx >> 4, r = idx & 15;
            tok_s[t][r] = tok32[(m0 + r) * SS + t];
        }
    }

    // Persistent weight fragments: 12 k-blocks x 4 n-frags = 192 VGPRs.
    const __bf16* Wt = is1 ? W1t : W2t;
    bf16x8 wreg[12][4];
    #pragma unroll
    for (int kk = 0; kk < 12; ++kk) {
        #pragma unroll
        for (int nf = 0; nf < 4; ++nf) {
            wreg[kk][nf] = load_bf8(
                Wt + (size_t)(n0 + nf * 16 + l16) * KK + w * 384 + kk * 32 + kg * 8);
        }
    }

    const float bn = (is1 ? b1 : b2)[n0 + (tid & 63)];

    __syncthreads();

    for (int i = 0; i <= SS; ++i) {
        if (i) group_barrier(ctr, (unsigned)(GRP * i));
        const bool active = is1 ? (i < SS) : (i >= 1);
        if (active) {
            const __bf16* h1cur = (i & 1) ? h1b : h1a;   // h1_i
            bf16x8 af[12];
            if (is1) {
                const float* erow = embW + (size_t)tok_s[i][l16] * EE;
                const __bf16* hrow = h1cur + (m0 + l16) * HH;
                #pragma unroll
                for (int kk = 0; kk < 12; ++kk) {
                    int k = w * 384 + kk * 32 + kg * 8;
                    af[kk] = (k < EE) ? cvt8(erow + k) : load_bf8(hrow + (k - EE));
                }
            } else {
                const __bf16* h2cur = ((i + 1) & 1) ? h2b : h2a;  // h2_{i-1}
                const __bf16* hrow = h1cur + (m0 + l16) * HH;
                const __bf16* h2row = h2cur + (m0 + l16) * EE;
                #pragma unroll
                for (int kk = 0; kk < 12; ++kk) {
                    int k = w * 384 + kk * 32 + kg * 8;
                    af[kk] = (k < HH) ? load_bf8(hrow + k) : load_bf8(h2row + (k - HH));
                }
            }

            f32x4 acc[4] = {{0,0,0,0},{0,0,0,0},{0,0,0,0},{0,0,0,0}};
            #pragma unroll
            for (int kk = 0; kk < 12; ++kk) {
                #pragma unroll
                for (int nf = 0; nf < 4; ++nf) {
                    acc[nf] = __builtin_amdgcn_mfma_f32_16x16x32_bf16(
                        af[kk], wreg[kk][nf], acc[nf], 0, 0, 0);
                }
            }

            // D layout: col = lane&15, row = (lane>>4)*4 + reg
            #pragma unroll
            for (int nf = 0; nf < 4; ++nf) {
                #pragma unroll
                for (int q = 0; q < 4; ++q)
                    red[w][kg * 4 + q][nf * 16 + l16] = acc[nf][q];
            }
            __syncthreads();

            const int n = tid & 63;
            __bf16* hnext;
            float* fout = nullptr;
            if (is1) {
                hnext = ((i + 1) & 1) ? h1b : h1a;
                if (i == SS - 1) fout = h1out;
            } else {
                hnext = (i & 1) ? h2b : h2a;
                if (i == SS) fout = h2out;
            }
            #pragma unroll
            for (int q = 0; q < 4; ++q) {
                int m = (tid >> 6) + q * 4;
                float s = red[0][m][n] + red[1][m][n] + red[2][m][n] + red[3][m][n];
                s = tanhf(s + bn);
                int gi = (m0 + m) * N + (n0 + n);
                hnext[gi] = (__bf16)s;
                if (fout) fout[gi] = s;
            }
        }
    }
}

// Fallback per-step kernel (round-1 proven path), used only if cooperative
// launch is unavailable. Blocks [0,128): GEMM1 16Mx32N; [128,192): GEMM2.
__global__ __launch_bounds__(256) void step_kernel(
    const int* __restrict__ tok32,
    const float* __restrict__ embW,
    const float* __restrict__ b1, const float* __restrict__ b2,
    const __bf16* __restrict__ W1t, const __bf16* __restrict__ W2t,
    const __bf16* __restrict__ h1cur, __bf16* __restrict__ h1next,
    const __bf16* __restrict__ h2cur, __bf16* __restrict__ h2next,
    float* __restrict__ h1f32, float* __restrict__ h2f32,
    int t, int g1, int g2) {
    const int bid = blockIdx.x;
    const bool is1 = bid < 128;
    if (is1 ? (g1 == 0) : (g2 == 0)) return;
    const int rb = is1 ? bid : (bid - 128);
    const int mi = rb & 3;
    const int ni = rb >> 2;
    const int m0 = mi << 4;
    const int n0 = ni << 5;
    const int N = is1 ? HH : EE;
    const int tid = threadIdx.x;
    const int w = tid >> 6;
    const int l = tid & 63;
    const int l16 = l & 15;
    const int kg = l >> 4;

    __shared__ int tok_s[16];
    __shared__ float red[4][16][33];

    if (is1 && tid < 16) tok_s[tid] = tok32[(m0 + tid) * SS + t];
    __syncthreads();

    const __bf16* Wt = is1 ? W1t : W2t;
    f32x4 acc0 = {0.f, 0.f, 0.f, 0.f};
    f32x4 acc1 = {0.f, 0.f, 0.f, 0.f};
    const int row = m0 + l16;
    const int kb = w * 384;

    #pragma unroll 4
    for (int kk = 0; kk < 384; kk += 32) {
        const int k = kb + kk + kg * 8;
        bf16x8 a;
        if (is1) {
            if (k < EE) a = cvt8(embW + (size_t)tok_s[l16] * EE + k);
            else        a = load_bf8(h1cur + row * HH + (k - EE));
        } else {
            if (k < HH) a = load_bf8(h1cur + row * HH + k);
            else        a = load_bf8(h2cur + row * EE + (k - HH));
        }
        bf16x8 bf0 = load_bf8(Wt + (size_t)(n0 + l16) * KK + k);
        bf16x8 bf1 = load_bf8(Wt + (size_t)(n0 + 16 + l16) * KK + k);
        acc0 = __builtin_amdgcn_mfma_f32_16x16x32_bf16(a, bf0, acc0, 0, 0, 0);
        acc1 = __builtin_amdgcn_mfma_f32_16x16x32_bf16(a, bf1, acc1, 0, 0, 0);
    }

    #pragma unroll
    for (int i = 0; i < 4; ++i) {
        red[w][kg * 4 + i][l16]      = acc0[i];
        red[w][kg * 4 + i][16 + l16] = acc1[i];
    }
    __syncthreads();

    const float* bias = is1 ? b1 : b2;
    for (int c = tid; c < 512; c += 256) {
        int m = c >> 5, n = c & 31;
        float s = red[0][m][n] + red[1][m][n] + red[2][m][n] + red[3][m][n];
        s = tanhf(s + bias[n0 + n]);
        int gi = (m0 + m) * N + (n0 + n);
        if (is1) {
            h1next[gi] = (__bf16)s;
            if (h1f32) h1f32[gi] = s;
        } else {
            h2next[gi] = (__bf16)s;
            if (h2f32) h2f32[gi] = s;
        }
    }
}

// out[64, V] = h2 @ emb_W^T + out_b.
__global__ __launch_bounds__(256) void proj_kernel(
    const __bf16* __restrict__ h2bf,
    const float* __restrict__ embW,
    const float* __restrict__ outb,
    float* __restrict__ out) {
    const int v0 = blockIdx.x << 6;
    const int tid = threadIdx.x;
    const int w = tid >> 6;
    const int l = tid & 63;
    const int l16 = l & 15, kg = l >> 4;
    const int vcol = v0 + w * 16 + l16;
    const int vr = vcol < VV ? vcol : VV - 1;
    f32x4 acc[4] = {{0,0,0,0},{0,0,0,0},{0,0,0,0},{0,0,0,0}};
    #pragma unroll 2
    for (int k0 = 0; k0 < EE; k0 += 32) {
        const int k = k0 + kg * 8;
        bf16x8 bfr = cvt8(embW + (size_t)vr * EE + k);
        #pragma unroll
        for (int mf = 0; mf < 4; ++mf) {
            bf16x8 a = load_bf8(h2bf + (mf * 16 + l16) * EE + k);
            acc[mf] = __builtin_amdgcn_mfma_f32_16x16x32_bf16(a, bfr, acc[mf], 0, 0, 0);
        }
    }
    if (vcol < VV) {
        const float bb = outb[vcol];
        #pragma unroll
        for (int mf = 0; mf < 4; ++mf) {
            #pragma unroll
            for (int i = 0; i < 4; ++i) {
                int b = mf * 16 + kg * 4 + i;
                out[(size_t)b * VV + vcol] = acc[mf][i] + bb;
            }
        }
    }
}

extern "C" void kernel_launch(void* const* d_in, const int* in_sizes, int n_in,
                              void* d_out, int out_size, void* d_ws, size_t ws_size,
                              hipStream_t stream) {
    const void* seq      = d_in[0];
    const float* init_h1 = (const float*)d_in[1];
    const float* init_h2 = (const float*)d_in[2];
    const float* embW    = (const float*)d_in[3];
    const float* W1      = (const float*)d_in[4];
    const float* b1      = (const float*)d_in[5];
    const float* W2      = (const float*)d_in[6];
    const float* b2      = (const float*)d_in[7];
    const float* outb    = (const float*)d_in[8];
    float* out = (float*)d_out;

    char* ws = (char*)d_ws;
    int* tok = (int*)ws;                 ws += (size_t)BB * SS * 4;
    __bf16* W1t = (__bf16*)ws;           ws += (size_t)HH * KK * 2;
    __bf16* W2t = (__bf16*)ws;           ws += (size_t)EE * KK * 2;
    __bf16* h1b0 = (__bf16*)ws;          ws += (size_t)BB * HH * 2;
    __bf16* h1b1 = (__bf16*)ws;          ws += (size_t)BB * HH * 2;
    __bf16* h2b0 = (__bf16*)ws;          ws += (size_t)BB * EE * 2;
    __bf16* h2b1 = (__bf16*)ws;          ws += (size_t)BB * EE * 2;
    unsigned* bar = (unsigned*)ws;       ws += 512;
    __bf16* h1bf[2] = {h1b0, h1b1};
    __bf16* h2bf[2] = {h2b0, h2b1};

    hipLaunchKernelGGL(tokens_kernel, dim3(128), dim3(256), 0, stream, seq, tok, bar);
    hipLaunchKernelGGL(transpose_kernel, dim3((KK / 32) * (HH / 32)), dim3(256), 0, stream,
                       W1, W1t, KK, HH);
    hipLaunchKernelGGL(transpose_kernel, dim3((KK / 32) * (EE / 32)), dim3(256), 0, stream,
                       W2, W2t, KK, EE);
    hipLaunchKernelGGL(init_kernel, dim3(256), dim3(256), 0, stream,
                       init_h1, init_h2, h1b0, h2b0);

    float* h1out = out + (size_t)BB * VV;
    float* h2out = h1out + (size_t)BB * HH;

    const int* tok_c = tok;
    const __bf16* W1t_c = W1t;
    const __bf16* W2t_c = W2t;
    void* args[] = {
        (void*)&tok_c, (void*)&embW, (void*)&b1, (void*)&b2,
        (void*)&W1t_c, (void*)&W2t_c,
        (void*)&h1b0, (void*)&h1b1, (void*)&h2b0, (void*)&h2b1,
        (void*)&h1out, (void*)&h2out, (void*)&bar
    };
    hipError_t err = hipLaunchCooperativeKernel((void*)rnn_persist, dim3(NWG), dim3(256),
                                                args, 0, stream);
    if (err != hipSuccess) {
        // Deterministic fallback: proven per-step path (round 1).
        for (int t = 0; t <= SS; ++t) {
            int g1 = (t < SS) ? 1 : 0;
            int g2 = (t >= 1) ? 1 : 0;
            const __bf16* h1cur = h1bf[t & 1];
            __bf16* h1next      = h1bf[(t + 1) & 1];
            const __bf16* h2cur = h2bf[(t + 1) & 1];
            __bf16* h2next      = h2bf[t & 1];
            float* h1f = (t == SS - 1) ? h1out : nullptr;
            float* h2f = (t == SS) ? h2out : nullptr;
            hipLaunchKernelGGL(step_kernel, dim3(192), dim3(256), 0, stream,
                               tok, embW, b1, b2, W1t, W2t,
                               h1cur, h1next, h2cur, h2next, h1f, h2f, t, g1, g2);
        }
    }

    hipLaunchKernelGGL(proj_kernel, dim3((VV + 63) / 64), dim3(256), 0, stream,
                       h2bf[0], embW, outb, out);
}

// Round 4
// 4927.382 us; speedup vs baseline: 1.2005x; 1.2005x over previous
//
#include <hip/hip_runtime.h>
#include <hip/hip_bf16.h>

#define BB 64
#define EE 512
#define HH 1024
#define KK 1536
#define VV 50257
#define SS 512

#define NWG1 64            // GEMM1: mi = bid&3 (4), ni = bid>>2 (16): 16M x 64N
#define NWG2 32            // GEMM2: mi = rb&3 (4),  ni = rb>>2 (8):  16M x 64N
#define NWG (NWG1 + NWG2)  // 96 blocks

typedef __bf16 bf16x8 __attribute__((ext_vector_type(8)));
typedef float f32x4 __attribute__((ext_vector_type(4)));

__device__ __forceinline__ bf16x8 load_bf8(const __bf16* p) {
    return *reinterpret_cast<const bf16x8*>(p);
}

__device__ __forceinline__ bf16x8 cvt8(const float* p) {
    f32x4 a = *reinterpret_cast<const f32x4*>(p);
    f32x4 b = *reinterpret_cast<const f32x4*>(p + 4);
    bf16x8 r;
    r[0] = (__bf16)a[0]; r[1] = (__bf16)a[1]; r[2] = (__bf16)a[2]; r[3] = (__bf16)a[3];
    r[4] = (__bf16)b[0]; r[5] = (__bf16)b[1]; r[6] = (__bf16)b[2]; r[7] = (__bf16)b[3];
    return r;
}

// Coherent (agent-scope, relaxed) 8B load/store: HW routes to the coherence
// point via sc bits — no buffer_wbl2 / buffer_inv cache maintenance ever.
__device__ __forceinline__ unsigned long long ld8c(const void* p) {
    return __hip_atomic_load((unsigned long long*)p, __ATOMIC_RELAXED,
                             __HIP_MEMORY_SCOPE_AGENT);
}
__device__ __forceinline__ void st8c(void* p, unsigned long long v) {
    __hip_atomic_store((unsigned long long*)p, v, __ATOMIC_RELAXED,
                       __HIP_MEMORY_SCOPE_AGENT);
}
__device__ __forceinline__ bf16x8 load_bf8_coh(const __bf16* p) {
    union { unsigned long long u[2]; bf16x8 v; } t;
    t.u[0] = ld8c(p);
    t.u[1] = ld8c(p + 4);
    return t.v;
}
__device__ __forceinline__ unsigned long long pack4(float s0, float s1, float s2, float s3) {
    union { __bf16 h[4]; unsigned long long u; } t;
    t.h[0] = (__bf16)s0; t.h[1] = (__bf16)s1; t.h[2] = (__bf16)s2; t.h[3] = (__bf16)s3;
    return t.u;
}

// Wait until all nslots slot-flags are >= target. Wave 0 polls in parallel.
__device__ __forceinline__ void wait_ge(unsigned* slots, int nslots, unsigned target) {
    if (threadIdx.x < 64) {
        const int l = threadIdx.x;
        const int idx = l < nslots ? l : 0;
        for (;;) {
            unsigned v = (unsigned)__hip_atomic_load(&slots[idx], __ATOMIC_RELAXED,
                                                     __HIP_MEMORY_SCOPE_AGENT);
            if (l >= nslots) v = target;
            if (__all((int)(v >= target))) break;
            __builtin_amdgcn_s_sleep(1);
        }
    }
    __syncthreads();
    asm volatile("" ::: "memory");
}

// Publish: all data stores of the whole block complete, then flag store.
__device__ __forceinline__ void signal(unsigned* slot, unsigned val) {
    asm volatile("s_waitcnt vmcnt(0) lgkmcnt(0)" ::: "memory");
    __syncthreads();
    if (threadIdx.x == 0)
        __hip_atomic_store(slot, val, __ATOMIC_RELAXED, __HIP_MEMORY_SCOPE_AGENT);
}

// Decode tokens to int32 (auto-detect int64 vs int32) + zero the 96 flag slots.
__global__ void tokens_kernel(const void* __restrict__ seq, int* __restrict__ tok,
                              unsigned* __restrict__ bar) {
    if (blockIdx.x == 0 && threadIdx.x < 96)
        __hip_atomic_store(&bar[threadIdx.x], 0u, __ATOMIC_RELAXED,
                           __HIP_MEMORY_SCOPE_AGENT);
    const unsigned* u = (const unsigned*)seq;
    bool is64 = true;
    #pragma unroll 1
    for (int i = 0; i < 64; ++i) {
        if (u[2 * i + 1] != 0u) { is64 = false; break; }
    }
    int i = blockIdx.x * 256 + threadIdx.x;
    if (i < BB * SS) tok[i] = is64 ? (int)u[2 * i] : (int)u[i];
}

// fp32 [R][C] row-major -> bf16 [C][R]
__global__ __launch_bounds__(256) void transpose_kernel(
    const float* __restrict__ in, __bf16* __restrict__ out, int R, int C) {
    __shared__ float t[32][33];
    int bc = C >> 5;
    int br = blockIdx.x / bc;
    int bco = blockIdx.x % bc;
    int R0 = br << 5, C0 = bco << 5;
    int c = threadIdx.x & 31, r0 = threadIdx.x >> 5;
    #pragma unroll
    for (int i = 0; i < 4; ++i) {
        int r = r0 + i * 8;
        t[r][c] = in[(size_t)(R0 + r) * C + C0 + c];
    }
    __syncthreads();
    #pragma unroll
    for (int i = 0; i < 4; ++i) {
        int r = r0 + i * 8;
        out[(size_t)(C0 + r) * R + R0 + c] = (__bf16)t[c][r];
    }
}

__global__ void init_kernel(const float* __restrict__ h1, const float* __restrict__ h2,
                            __bf16* __restrict__ h1bf, __bf16* __restrict__ h2bf) {
    int i = blockIdx.x * 256 + threadIdx.x;
    if (i < BB * HH) h1bf[i] = (__bf16)h1[i];
    if (i < BB * EE) h2bf[i] = (__bf16)h2[i];
}

// Persistent pipelined recurrence, fence-free producer/consumer flags.
// GEMM1 block (mi,ni): iter i in [0,SS): h1_{i+1}[16 rows x 64 cols] =
//   tanh([e_i, h1_i] W1); signals f1[mi][ni] = i+1.
// GEMM2 block (mi,ni): iter i in [1,SS]: h2_i = tanh([h1_i, h2_{i-1}] W2);
//   signals f2[mi][ni] = i.
// Waits: GEMM1@i: f2>=i-1 (WAR on h1_{i-1}), f1>=i (RAW h1_i).
//        GEMM2@i: f2>=i-1 (RAW h2_{i-1} + WAR), f1>=i (RAW h1_i).
// h-state moves via relaxed agent-scope atomics (coherent, no cache flush);
// read-only data (emb, weights, bias, tokens) stays on the cached path.
__global__ __launch_bounds__(256, 1) void rnn_persist(
    const int* __restrict__ tok32, const float* __restrict__ embW,
    const float* __restrict__ b1, const float* __restrict__ b2,
    const __bf16* __restrict__ W1t, const __bf16* __restrict__ W2t,
    __bf16* __restrict__ h1a, __bf16* __restrict__ h1b,
    __bf16* __restrict__ h2a, __bf16* __restrict__ h2b,
    float* __restrict__ h1out, float* __restrict__ h2out,
    unsigned* __restrict__ bar) {
    const int bid = blockIdx.x;
    const bool is1 = bid < NWG1;
    const int rb = is1 ? bid : bid - NWG1;
    const int mi = rb & 3;
    const int ni = rb >> 2;
    const int m0 = mi << 4;
    const int n0 = ni << 6;
    const int tid = threadIdx.x;
    const int w = tid >> 6;
    const int l = tid & 63;
    const int l16 = l & 15;
    const int kg = l >> 4;
    unsigned* f1s = bar + mi * 16;       // 16 GEMM1 slots per mi-group
    unsigned* f2s = bar + 64 + mi * 8;   // 8 GEMM2 slots per mi-group

    __shared__ int tok_s[SS][16];
    __shared__ float red[4][16][66];

    if (is1) {
        for (int idx = tid; idx < SS * 16; idx += 256) {
            int t = idx >> 4, r = idx & 15;
            tok_s[t][r] = tok32[(m0 + r) * SS + t];
        }
    }

    // Persistent weight fragments: 12 k-blocks x 4 n-frags = 192 VGPRs.
    const __bf16* Wt = is1 ? W1t : W2t;
    bf16x8 wreg[12][4];
    #pragma unroll
    for (int kk = 0; kk < 12; ++kk) {
        #pragma unroll
        for (int nf = 0; nf < 4; ++nf) {
            wreg[kk][nf] = load_bf8(
                Wt + (size_t)(n0 + nf * 16 + l16) * KK + w * 384 + kk * 32 + kg * 8);
        }
    }
    // Pin fragments in VGPRs: opaque asm writes block the compiler from
    // sinking/rematerializing the loads inside the loop (round-3 bug:
    // VGPR_Count=144 proved weights were re-fetched every iteration).
    {
        f32x4* wr = reinterpret_cast<f32x4*>(&wreg[0][0]);
        #pragma unroll
        for (int q = 0; q < 48; ++q) asm volatile("" : "+v"(wr[q]));
    }

    // Epilogue mapping: thread -> (m = tid>>4, n4 = (tid&15)*4).
    const f32x4 bb4 = *reinterpret_cast<const f32x4*>(
        (is1 ? b1 : b2) + n0 + (tid & 15) * 4);
    const int em = tid >> 4;
    const int en4 = (tid & 15) * 4;

    __syncthreads();

    if (is1) {
        for (int i = 0; i < SS; ++i) {
            f32x4 acc[4] = {{0,0,0,0},{0,0,0,0},{0,0,0,0},{0,0,0,0}};
            // Pre-wait: embedding-part MFMAs (read-only inputs, cached path).
            const float* erow = embW + (size_t)tok_s[i][l16] * EE;
            #pragma unroll
            for (int kk = 0; kk < 12; ++kk) {
                int k = w * 384 + kk * 32 + kg * 8;
                if (k < EE) {
                    bf16x8 a = cvt8(erow + k);
                    #pragma unroll
                    for (int nf = 0; nf < 4; ++nf)
                        acc[nf] = __builtin_amdgcn_mfma_f32_16x16x32_bf16(
                            a, wreg[kk][nf], acc[nf], 0, 0, 0);
                }
            }
            if (i >= 2) wait_ge(f2s, 8, (unsigned)(i - 1));
            if (i >= 1) wait_ge(f1s, 16, (unsigned)i);
            // Critical path: coherent h1_i loads + MFMAs.
            const __bf16* hrow = ((i & 1) ? h1b : h1a) + (m0 + l16) * HH;
            #pragma unroll
            for (int kk = 0; kk < 12; ++kk) {
                int k = w * 384 + kk * 32 + kg * 8;
                if (k >= EE) {
                    bf16x8 a = load_bf8_coh(hrow + (k - EE));
                    #pragma unroll
                    for (int nf = 0; nf < 4; ++nf)
                        acc[nf] = __builtin_amdgcn_mfma_f32_16x16x32_bf16(
                            a, wreg[kk][nf], acc[nf], 0, 0, 0);
                }
            }
            #pragma unroll
            for (int nf = 0; nf < 4; ++nf)
                #pragma unroll
                for (int q = 0; q < 4; ++q)
                    red[w][kg * 4 + q][nf * 16 + l16] = acc[nf][q];
            __syncthreads();

            float s[4];
            #pragma unroll
            for (int j = 0; j < 4; ++j) {
                int n = en4 + j;
                s[j] = tanhf(red[0][em][n] + red[1][em][n] + red[2][em][n] +
                             red[3][em][n] + bb4[j]);
            }
            __bf16* hnext = (((i + 1) & 1) ? h1b : h1a);
            st8c(hnext + (m0 + em) * HH + n0 + en4, pack4(s[0], s[1], s[2], s[3]));
            if (i == SS - 1) {
                f32x4 fo = {s[0], s[1], s[2], s[3]};
                *reinterpret_cast<f32x4*>(h1out + (m0 + em) * HH + n0 + en4) = fo;
            }
            signal(&f1s[ni], (unsigned)(i + 1));
        }
    } else {
        for (int i = 1; i <= SS; ++i) {
            f32x4 acc[4] = {{0,0,0,0},{0,0,0,0},{0,0,0,0},{0,0,0,0}};
            if (i >= 2) wait_ge(f2s, 8, (unsigned)(i - 1));
            // h2_{i-1}-part MFMAs (ready after f2 wait; off critical path).
            const __bf16* h2row = (((i + 1) & 1) ? h2b : h2a) + (m0 + l16) * EE;
            #pragma unroll
            for (int kk = 0; kk < 12; ++kk) {
                int k = w * 384 + kk * 32 + kg * 8;
                if (k >= HH) {
                    bf16x8 a = load_bf8_coh(h2row + (k - HH));
                    #pragma unroll
                    for (int nf = 0; nf < 4; ++nf)
                        acc[nf] = __builtin_amdgcn_mfma_f32_16x16x32_bf16(
                            a, wreg[kk][nf], acc[nf], 0, 0, 0);
                }
            }
            wait_ge(f1s, 16, (unsigned)i);
            const __bf16* hrow = ((i & 1) ? h1b : h1a) + (m0 + l16) * HH;
            #pragma unroll
            for (int kk = 0; kk < 12; ++kk) {
                int k = w * 384 + kk * 32 + kg * 8;
                if (k < HH) {
                    bf16x8 a = load_bf8_coh(hrow + k);
                    #pragma unroll
                    for (int nf = 0; nf < 4; ++nf)
                        acc[nf] = __builtin_amdgcn_mfma_f32_16x16x32_bf16(
                            a, wreg[kk][nf], acc[nf], 0, 0, 0);
                }
            }
            #pragma unroll
            for (int nf = 0; nf < 4; ++nf)
                #pragma unroll
                for (int q = 0; q < 4; ++q)
                    red[w][kg * 4 + q][nf * 16 + l16] = acc[nf][q];
            __syncthreads();

            float s[4];
            #pragma unroll
            for (int j = 0; j < 4; ++j) {
                int n = en4 + j;
                s[j] = tanhf(red[0][em][n] + red[1][em][n] + red[2][em][n] +
                             red[3][em][n] + bb4[j]);
            }
            __bf16* hnext = ((i & 1) ? h2b : h2a);
            st8c(hnext + (m0 + em) * EE + n0 + en4, pack4(s[0], s[1], s[2], s[3]));
            if (i == SS) {
                f32x4 fo = {s[0], s[1], s[2], s[3]};
                *reinterpret_cast<f32x4*>(h2out + (m0 + em) * EE + n0 + en4) = fo;
            }
            signal(&f2s[ni], (unsigned)i);
        }
    }
}

// Fallback per-step kernel (round-1 proven path), used only if cooperative
// launch is unavailable.
__global__ __launch_bounds__(256) void step_kernel(
    const int* __restrict__ tok32,
    const float* __restrict__ embW,
    const float* __restrict__ b1, const float* __restrict__ b2,
    const __bf16* __restrict__ W1t, const __bf16* __restrict__ W2t,
    const __bf16* __restrict__ h1cur, __bf16* __restrict__ h1next,
    const __bf16* __restrict__ h2cur, __bf16* __restrict__ h2next,
    float* __restrict__ h1f32, float* __restrict__ h2f32,
    int t, int g1, int g2) {
    const int bid = blockIdx.x;
    const bool is1 = bid < 128;
    if (is1 ? (g1 == 0) : (g2 == 0)) return;
    const int rb = is1 ? bid : (bid - 128);
    const int mi = rb & 3;
    const int ni = rb >> 2;
    const int m0 = mi << 4;
    const int n0 = ni << 5;
    const int N = is1 ? HH : EE;
    const int tid = threadIdx.x;
    const int w = tid >> 6;
    const int l = tid & 63;
    const int l16 = l & 15;
    const int kg = l >> 4;

    __shared__ int tok_s[16];
    __shared__ float red[4][16][33];

    if (is1 && tid < 16) tok_s[tid] = tok32[(m0 + tid) * SS + t];
    __syncthreads();

    const __bf16* Wt = is1 ? W1t : W2t;
    f32x4 acc0 = {0.f, 0.f, 0.f, 0.f};
    f32x4 acc1 = {0.f, 0.f, 0.f, 0.f};
    const int row = m0 + l16;
    const int kb = w * 384;

    #pragma unroll 4
    for (int kk = 0; kk < 384; kk += 32) {
        const int k = kb + kk + kg * 8;
        bf16x8 a;
        if (is1) {
            if (k < EE) a = cvt8(embW + (size_t)tok_s[l16] * EE + k);
            else        a = load_bf8(h1cur + row * HH + (k - EE));
        } else {
            if (k < HH) a = load_bf8(h1cur + row * HH + k);
            else        a = load_bf8(h2cur + row * EE + (k - HH));
        }
        bf16x8 bf0 = load_bf8(Wt + (size_t)(n0 + l16) * KK + k);
        bf16x8 bf1 = load_bf8(Wt + (size_t)(n0 + 16 + l16) * KK + k);
        acc0 = __builtin_amdgcn_mfma_f32_16x16x32_bf16(a, bf0, acc0, 0, 0, 0);
        acc1 = __builtin_amdgcn_mfma_f32_16x16x32_bf16(a, bf1, acc1, 0, 0, 0);
    }

    #pragma unroll
    for (int i = 0; i < 4; ++i) {
        red[w][kg * 4 + i][l16]      = acc0[i];
        red[w][kg * 4 + i][16 + l16] = acc1[i];
    }
    __syncthreads();

    const float* bias = is1 ? b1 : b2;
    for (int c = tid; c < 512; c += 256) {
        int m = c >> 5, n = c & 31;
        float s = red[0][m][n] + red[1][m][n] + red[2][m][n] + red[3][m][n];
        s = tanhf(s + bias[n0 + n]);
        int gi = (m0 + m) * N + (n0 + n);
        if (is1) {
            h1next[gi] = (__bf16)s;
            if (h1f32) h1f32[gi] = s;
        } else {
            h2next[gi] = (__bf16)s;
            if (h2f32) h2f32[gi] = s;
        }
    }
}

// out[64, V] = h2 @ emb_W^T + out_b.
__global__ __launch_bounds__(256) void proj_kernel(
    const __bf16* __restrict__ h2bf,
    const float* __restrict__ embW,
    const float* __restrict__ outb,
    float* __restrict__ out) {
    const int v0 = blockIdx.x << 6;
    const int tid = threadIdx.x;
    const int w = tid >> 6;
    const int l = tid & 63;
    const int l16 = l & 15, kg = l >> 4;
    const int vcol = v0 + w * 16 + l16;
    const int vr = vcol < VV ? vcol : VV - 1;
    f32x4 acc[4] = {{0,0,0,0},{0,0,0,0},{0,0,0,0},{0,0,0,0}};
    #pragma unroll 2
    for (int k0 = 0; k0 < EE; k0 += 32) {
        const int k = k0 + kg * 8;
        bf16x8 bfr = cvt8(embW + (size_t)vr * EE + k);
        #pragma unroll
        for (int mf = 0; mf < 4; ++mf) {
            bf16x8 a = load_bf8(h2bf + (mf * 16 + l16) * EE + k);
            acc[mf] = __builtin_amdgcn_mfma_f32_16x16x32_bf16(a, bfr, acc[mf], 0, 0, 0);
        }
    }
    if (vcol < VV) {
        const float bb = outb[vcol];
        #pragma unroll
        for (int mf = 0; mf < 4; ++mf) {
            #pragma unroll
            for (int i = 0; i < 4; ++i) {
                int b = mf * 16 + kg * 4 + i;
                out[(size_t)b * VV + vcol] = acc[mf][i] + bb;
            }
        }
    }
}

extern "C" void kernel_launch(void* const* d_in, const int* in_sizes, int n_in,
                              void* d_out, int out_size, void* d_ws, size_t ws_size,
                              hipStream_t stream) {
    const void* seq      = d_in[0];
    const float* init_h1 = (const float*)d_in[1];
    const float* init_h2 = (const float*)d_in[2];
    const float* embW    = (const float*)d_in[3];
    const float* W1      = (const float*)d_in[4];
    const float* b1      = (const float*)d_in[5];
    const float* W2      = (const float*)d_in[6];
    const float* b2      = (const float*)d_in[7];
    const float* outb    = (const float*)d_in[8];
    float* out = (float*)d_out;

    char* ws = (char*)d_ws;
    int* tok = (int*)ws;                 ws += (size_t)BB * SS * 4;
    __bf16* W1t = (__bf16*)ws;           ws += (size_t)HH * KK * 2;
    __bf16* W2t = (__bf16*)ws;           ws += (size_t)EE * KK * 2;
    __bf16* h1b0 = (__bf16*)ws;          ws += (size_t)BB * HH * 2;
    __bf16* h1b1 = (__bf16*)ws;          ws += (size_t)BB * HH * 2;
    __bf16* h2b0 = (__bf16*)ws;          ws += (size_t)BB * EE * 2;
    __bf16* h2b1 = (__bf16*)ws;          ws += (size_t)BB * EE * 2;
    unsigned* bar = (unsigned*)ws;       ws += 512;
    __bf16* h1bf[2] = {h1b0, h1b1};
    __bf16* h2bf[2] = {h2b0, h2b1};

    hipLaunchKernelGGL(tokens_kernel, dim3(128), dim3(256), 0, stream, seq, tok, bar);
    hipLaunchKernelGGL(transpose_kernel, dim3((KK / 32) * (HH / 32)), dim3(256), 0, stream,
                       W1, W1t, KK, HH);
    hipLaunchKernelGGL(transpose_kernel, dim3((KK / 32) * (EE / 32)), dim3(256), 0, stream,
                       W2, W2t, KK, EE);
    hipLaunchKernelGGL(init_kernel, dim3(256), dim3(256), 0, stream,
                       init_h1, init_h2, h1b0, h2b0);

    float* h1out = out + (size_t)BB * VV;
    float* h2out = h1out + (size_t)BB * HH;

    const int* tok_c = tok;
    const __bf16* W1t_c = W1t;
    const __bf16* W2t_c = W2t;
    void* args[] = {
        (void*)&tok_c, (void*)&embW, (void*)&b1, (void*)&b2,
        (void*)&W1t_c, (void*)&W2t_c,
        (void*)&h1b0, (void*)&h1b1, (void*)&h2b0, (void*)&h2b1,
        (void*)&h1out, (void*)&h2out, (void*)&bar
    };
    hipError_t err = hipLaunchCooperativeKernel((void*)rnn_persist, dim3(NWG), dim3(256),
                                                args, 0, stream);
    if (err != hipSuccess) {
        // Deterministic fallback: proven per-step path (round 1).
        for (int t = 0; t <= SS; ++t) {
            int g1 = (t < SS) ? 1 : 0;
            int g2 = (t >= 1) ? 1 : 0;
            const __bf16* h1cur = h1bf[t & 1];
            __bf16* h1next      = h1bf[(t + 1) & 1];
            const __bf16* h2cur = h2bf[(t + 1) & 1];
            __bf16* h2next      = h2bf[t & 1];
            float* h1f = (t == SS - 1) ? h1out : nullptr;
            float* h2f = (t == SS) ? h2out : nullptr;
            hipLaunchKernelGGL(step_kernel, dim3(192), dim3(256), 0, stream,
                               tok, embW, b1, b2, W1t, W2t,
                               h1cur, h1next, h2cur, h2next, h1f, h2f, t, g1, g2);
        }
    }

    hipLaunchKernelGGL(proj_kernel, dim3((VV + 63) / 64), dim3(256), 0, stream,
                       h2bf[0], embW, outb, out);
}

// Round 5
// 3482.347 us; speedup vs baseline: 1.6987x; 1.4150x over previous
//
#include <hip/hip_runtime.h>
#include <hip/hip_bf16.h>

#define BB 64
#define EE 512
#define HH 1024
#define KK 1536
#define VV 50257
#define SS 512

#define NWG 64   // merged blocks: mi = bid&3 (16 rows), ni = bid>>2 (16 col-tiles)

typedef __bf16 bf16x8 __attribute__((ext_vector_type(8)));
typedef float f32x4 __attribute__((ext_vector_type(4)));

__device__ __forceinline__ bf16x8 load_bf8(const __bf16* p) {
    return *reinterpret_cast<const bf16x8*>(p);
}

__device__ __forceinline__ bf16x8 cvt8(const float* p) {
    f32x4 a = *reinterpret_cast<const f32x4*>(p);
    f32x4 b = *reinterpret_cast<const f32x4*>(p + 4);
    bf16x8 r;
    r[0] = (__bf16)a[0]; r[1] = (__bf16)a[1]; r[2] = (__bf16)a[2]; r[3] = (__bf16)a[3];
    r[4] = (__bf16)b[0]; r[5] = (__bf16)b[1]; r[6] = (__bf16)b[2]; r[7] = (__bf16)b[3];
    return r;
}

// Coherent (agent-scope, relaxed) loads/stores: routed to the coherence point
// via sc bits — no buffer_wbl2 / buffer_inv cache maintenance ever.
__device__ __forceinline__ unsigned long long ld8c(const void* p) {
    return __hip_atomic_load((unsigned long long*)p, __ATOMIC_RELAXED,
                             __HIP_MEMORY_SCOPE_AGENT);
}
__device__ __forceinline__ void st8c(void* p, unsigned long long v) {
    __hip_atomic_store((unsigned long long*)p, v, __ATOMIC_RELAXED,
                       __HIP_MEMORY_SCOPE_AGENT);
}
__device__ __forceinline__ void st4c(void* p, unsigned v) {
    __hip_atomic_store((unsigned*)p, v, __ATOMIC_RELAXED, __HIP_MEMORY_SCOPE_AGENT);
}
__device__ __forceinline__ bf16x8 load_bf8_coh(const __bf16* p) {
    union { unsigned long long u[2]; bf16x8 v; } t;
    t.u[0] = ld8c(p);
    t.u[1] = ld8c(p + 4);
    return t.v;
}
__device__ __forceinline__ unsigned long long pack4(float s0, float s1, float s2, float s3) {
    union { __bf16 h[4]; unsigned long long u; } t;
    t.h[0] = (__bf16)s0; t.h[1] = (__bf16)s1; t.h[2] = (__bf16)s2; t.h[3] = (__bf16)s3;
    return t.u;
}
__device__ __forceinline__ unsigned pack2(float s0, float s1) {
    union { __bf16 h[2]; unsigned u; } t;
    t.h[0] = (__bf16)s0; t.h[1] = (__bf16)s1;
    return t.u;
}

// Wait until all nslots slot-flags are >= target. Wave 0 polls (lane-parallel).
__device__ __forceinline__ void wait_ge(unsigned* slots, int nslots, unsigned target) {
    if (threadIdx.x < 64) {
        const int l = threadIdx.x;
        const int idx = l < nslots ? l : 0;
        for (;;) {
            unsigned v = (unsigned)__hip_atomic_load(&slots[idx], __ATOMIC_RELAXED,
                                                     __HIP_MEMORY_SCOPE_AGENT);
            if (l >= nslots) v = target;
            if (__all((int)(v >= target))) break;
        }
    }
    __syncthreads();
    asm volatile("" ::: "memory");
}

// Publish: all data stores of the whole block complete, then flag store.
__device__ __forceinline__ void signal(unsigned* slot, unsigned val) {
    asm volatile("s_waitcnt vmcnt(0) lgkmcnt(0)" ::: "memory");
    __syncthreads();
    if (threadIdx.x == 0)
        __hip_atomic_store(slot, val, __ATOMIC_RELAXED, __HIP_MEMORY_SCOPE_AGENT);
}

// Decode tokens to int32 (auto-detect int64 vs int32) + zero the flag slots.
__global__ void tokens_kernel(const void* __restrict__ seq, int* __restrict__ tok,
                              unsigned* __restrict__ bar) {
    if (blockIdx.x == 0 && threadIdx.x < 128)
        __hip_atomic_store(&bar[threadIdx.x], 0u, __ATOMIC_RELAXED,
                           __HIP_MEMORY_SCOPE_AGENT);
    const unsigned* u = (const unsigned*)seq;
    bool is64 = true;
    #pragma unroll 1
    for (int i = 0; i < 64; ++i) {
        if (u[2 * i + 1] != 0u) { is64 = false; break; }
    }
    int i = blockIdx.x * 256 + threadIdx.x;
    if (i < BB * SS) tok[i] = is64 ? (int)u[2 * i] : (int)u[i];
}

// fp32 [R][C] row-major -> bf16 [C][R]
__global__ __launch_bounds__(256) void transpose_kernel(
    const float* __restrict__ in, __bf16* __restrict__ out, int R, int C) {
    __shared__ float t[32][33];
    int bc = C >> 5;
    int br = blockIdx.x / bc;
    int bco = blockIdx.x % bc;
    int R0 = br << 5, C0 = bco << 5;
    int c = threadIdx.x & 31, r0 = threadIdx.x >> 5;
    #pragma unroll
    for (int i = 0; i < 4; ++i) {
        int r = r0 + i * 8;
        t[r][c] = in[(size_t)(R0 + r) * C + C0 + c];
    }
    __syncthreads();
    #pragma unroll
    for (int i = 0; i < 4; ++i) {
        int r = r0 + i * 8;
        out[(size_t)(C0 + r) * R + R0 + c] = (__bf16)t[c][r];
    }
}

__global__ void init_kernel(const float* __restrict__ h1, const float* __restrict__ h2,
                            __bf16* __restrict__ h1bf, __bf16* __restrict__ h2bf) {
    int i = blockIdx.x * 256 + threadIdx.x;
    if (i < BB * HH) h1bf[i] = (__bf16)h1[i];
    if (i < BB * EE) h2bf[i] = (__bf16)h2[i];
}

// Persistent merged-role recurrence, ONE wait + ONE signal per step.
// Block (mi,ni), iteration i in [0,SS]:
//   G1 part (i<SS):  h1_{i+1} tile [16 x 64]  = tanh([e_i, h1_i] W1)
//   G2 part (i>=1):  h2_i     tile [16 x 32]  = tanh([h1_i, h2_{i-1}] W2)
// Both inputs were published at end of step i-1 -> single wait flags >= i.
// Depth-4 ring buffers make every WAR constraint implied by that same wait
// (skew between blocks is <=1 step; overwritten data is 3 steps stale).
// Wave w owns K-slices {w+4t, t=0..11} (strided): 4 emb slices run pre-wait,
// and G2's h1-part fragments coincide exactly with G1's (index algebra:
// G2 slice j' = j-16 stays in the same wave since j' ≡ j (mod 4)).
__global__ __launch_bounds__(256, 1) void rnn_persist2(
    const int* __restrict__ tok32, const float* __restrict__ embW,
    const float* __restrict__ b1, const float* __restrict__ b2,
    const __bf16* __restrict__ W1t, const __bf16* __restrict__ W2t,
    __bf16* __restrict__ h1r, __bf16* __restrict__ h2r,
    float* __restrict__ h1out, float* __restrict__ h2out,
    unsigned* __restrict__ bar) {
    const int bid = blockIdx.x;
    const int mi = bid & 3;
    const int ni = bid >> 2;
    const int m0 = mi << 4;
    const int n0 = ni << 6;      // G1 column tile
    const int n20 = ni << 5;     // G2 column tile
    const int tid = threadIdx.x;
    const int w = tid >> 6;
    const int l = tid & 63;
    const int l16 = l & 15;
    const int kg = l >> 4;
    unsigned* flags = bar + mi * 32;  // 16 slots per mi-group, 128B-separated

    __shared__ int tok_s[SS][16];
    __shared__ float red[4][16][66];

    for (int idx = tid; idx < SS * 16; idx += 256) {
        int t = idx >> 4, r = idx & 15;
        tok_s[t][r] = tok32[(m0 + r) * SS + t];
    }

    // Register-resident weights: wave w holds K-slices {w+4t}.
    // wg1: 12x4 frags (192 regs), wg2: 12x2 frags (96 regs).
    bf16x8 wg1[12][4];
    bf16x8 wg2[12][2];
    #pragma unroll
    for (int t = 0; t < 12; ++t) {
        const int kb = 32 * (w + 4 * t) + kg * 8;
        #pragma unroll
        for (int nf = 0; nf < 4; ++nf)
            wg1[t][nf] = load_bf8(W1t + (size_t)(n0 + nf * 16 + l16) * KK + kb);
        #pragma unroll
        for (int nf = 0; nf < 2; ++nf)
            wg2[t][nf] = load_bf8(W2t + (size_t)(n20 + nf * 16 + l16) * KK + kb);
    }
    {   // Pin in the register file (round-3 lesson: unpinned loads get sunk
        // into the loop and re-fetched every iteration).
        f32x4* p1 = reinterpret_cast<f32x4*>(&wg1[0][0]);
        #pragma unroll
        for (int q = 0; q < 48; ++q) asm volatile("" : "+v"(p1[q]));
        f32x4* p2 = reinterpret_cast<f32x4*>(&wg2[0][0]);
        #pragma unroll
        for (int q = 0; q < 24; ++q) asm volatile("" : "+v"(p2[q]));
    }

    const f32x4 bb4 = *reinterpret_cast<const f32x4*>(b1 + n0 + (tid & 15) * 4);
    const float b2a = b2[n20 + (tid & 15) * 2];
    const float b2b = b2[n20 + (tid & 15) * 2 + 1];
    const int em = tid >> 4;
    const int en4 = (tid & 15) * 4;
    const int en2 = (tid & 15) * 2;

    __syncthreads();

    for (int i = 0; i <= SS; ++i) {
        const __bf16* h1i = h1r + (size_t)(i & 3) * BB * HH;        // h1_i
        __bf16*       h1n = h1r + (size_t)((i + 1) & 3) * BB * HH;  // h1_{i+1}
        const __bf16* h2p = h2r + (size_t)((i + 3) & 3) * BB * EE;  // h2_{i-1}
        __bf16*       h2n = h2r + (size_t)(i & 3) * BB * EE;        // h2_i

        f32x4 acc1[4] = {{0,0,0,0},{0,0,0,0},{0,0,0,0},{0,0,0,0}};
        if (i < SS) {
            // Pre-wait work: embedding-part MFMAs (read-only, cached path).
            const float* erow = embW + (size_t)tok_s[i][l16] * EE;
            #pragma unroll
            for (int t = 0; t < 4; ++t) {
                bf16x8 ae = cvt8(erow + 32 * (w + 4 * t) + kg * 8);
                #pragma unroll
                for (int nf = 0; nf < 4; ++nf)
                    acc1[nf] = __builtin_amdgcn_mfma_f32_16x16x32_bf16(
                        ae, wg1[t][nf], acc1[nf], 0, 0, 0);
            }
        }

        if (i >= 1) wait_ge(flags, 16, (unsigned)i);

        // h1_i fragments: used by G1 (slices 4..11) AND G2 (slices 0..7).
        const __bf16* h1row = h1i + (m0 + l16) * HH;
        bf16x8 ah[8];
        #pragma unroll
        for (int u = 0; u < 8; ++u)
            ah[u] = load_bf8_coh(h1row + 32 * (w + 4 * u) + kg * 8);

        bf16x8 a2[4];
        if (i >= 1) {
            const __bf16* h2row = h2p + (m0 + l16) * EE;
            #pragma unroll
            for (int u = 0; u < 4; ++u)
                a2[u] = load_bf8_coh(h2row + 32 * (w + 4 * u) + kg * 8);
        }

        if (i < SS) {
            #pragma unroll
            for (int u = 0; u < 8; ++u)
                #pragma unroll
                for (int nf = 0; nf < 4; ++nf)
                    acc1[nf] = __builtin_amdgcn_mfma_f32_16x16x32_bf16(
                        ah[u], wg1[u + 4][nf], acc1[nf], 0, 0, 0);
        }
        f32x4 acc2[2] = {{0,0,0,0},{0,0,0,0}};
        if (i >= 1) {
            #pragma unroll
            for (int u = 0; u < 8; ++u)
                #pragma unroll
                for (int nf = 0; nf < 2; ++nf)
                    acc2[nf] = __builtin_amdgcn_mfma_f32_16x16x32_bf16(
                        ah[u], wg2[u][nf], acc2[nf], 0, 0, 0);
            #pragma unroll
            for (int u = 0; u < 4; ++u)
                #pragma unroll
                for (int nf = 0; nf < 2; ++nf)
                    acc2[nf] = __builtin_amdgcn_mfma_f32_16x16x32_bf16(
                        a2[u], wg2[u + 8][nf], acc2[nf], 0, 0, 0);
        }

        // Epilogue G1: D layout col=lane&15, row=(lane>>4)*4+reg.
        if (i < SS) {
            #pragma unroll
            for (int nf = 0; nf < 4; ++nf)
                #pragma unroll
                for (int q = 0; q < 4; ++q)
                    red[w][kg * 4 + q][nf * 16 + l16] = acc1[nf][q];
            __syncthreads();
            float s[4];
            #pragma unroll
            for (int j = 0; j < 4; ++j) {
                int n = en4 + j;
                s[j] = tanhf(red[0][em][n] + red[1][em][n] + red[2][em][n] +
                             red[3][em][n] + bb4[j]);
            }
            st8c(h1n + (m0 + em) * HH + n0 + en4, pack4(s[0], s[1], s[2], s[3]));
            if (i == SS - 1) {
                f32x4 fo = {s[0], s[1], s[2], s[3]};
                *reinterpret_cast<f32x4*>(h1out + (m0 + em) * HH + n0 + en4) = fo;
            }
            __syncthreads();  // before red reuse by G2 epilogue
        }
        // Epilogue G2.
        if (i >= 1) {
            #pragma unroll
            for (int nf = 0; nf < 2; ++nf)
                #pragma unroll
                for (int q = 0; q < 4; ++q)
                    red[w][kg * 4 + q][nf * 16 + l16] = acc2[nf][q];
            __syncthreads();
            float s0 = tanhf(red[0][em][en2] + red[1][em][en2] + red[2][em][en2] +
                             red[3][em][en2] + b2a);
            float s1 = tanhf(red[0][em][en2 + 1] + red[1][em][en2 + 1] +
                             red[2][em][en2 + 1] + red[3][em][en2 + 1] + b2b);
            st4c(h2n + (m0 + em) * EE + n20 + en2, pack2(s0, s1));
            if (i == SS) {
                h2out[(m0 + em) * EE + n20 + en2] = s0;
                h2out[(m0 + em) * EE + n20 + en2 + 1] = s1;
            }
        }
        if (i < SS) signal(&flags[ni], (unsigned)(i + 1));
    }
}

// Fallback per-step kernel (round-1 proven path), used only if cooperative
// launch is unavailable.
__global__ __launch_bounds__(256) void step_kernel(
    const int* __restrict__ tok32,
    const float* __restrict__ embW,
    const float* __restrict__ b1, const float* __restrict__ b2,
    const __bf16* __restrict__ W1t, const __bf16* __restrict__ W2t,
    const __bf16* __restrict__ h1cur, __bf16* __restrict__ h1next,
    const __bf16* __restrict__ h2cur, __bf16* __restrict__ h2next,
    float* __restrict__ h1f32, float* __restrict__ h2f32,
    int t, int g1, int g2) {
    const int bid = blockIdx.x;
    const bool is1 = bid < 128;
    if (is1 ? (g1 == 0) : (g2 == 0)) return;
    const int rb = is1 ? bid : (bid - 128);
    const int mi = rb & 3;
    const int ni = rb >> 2;
    const int m0 = mi << 4;
    const int n0 = ni << 5;
    const int N = is1 ? HH : EE;
    const int tid = threadIdx.x;
    const int w = tid >> 6;
    const int l = tid & 63;
    const int l16 = l & 15;
    const int kg = l >> 4;

    __shared__ int tok_s[16];
    __shared__ float red[4][16][33];

    if (is1 && tid < 16) tok_s[tid] = tok32[(m0 + tid) * SS + t];
    __syncthreads();

    const __bf16* Wt = is1 ? W1t : W2t;
    f32x4 acc0 = {0.f, 0.f, 0.f, 0.f};
    f32x4 acc1 = {0.f, 0.f, 0.f, 0.f};
    const int row = m0 + l16;
    const int kb = w * 384;

    #pragma unroll 4
    for (int kk = 0; kk < 384; kk += 32) {
        const int k = kb + kk + kg * 8;
        bf16x8 a;
        if (is1) {
            if (k < EE) a = cvt8(embW + (size_t)tok_s[l16] * EE + k);
            else        a = load_bf8(h1cur + row * HH + (k - EE));
        } else {
            if (k < HH) a = load_bf8(h1cur + row * HH + k);
            else        a = load_bf8(h2cur + row * EE + (k - HH));
        }
        bf16x8 bf0 = load_bf8(Wt + (size_t)(n0 + l16) * KK + k);
        bf16x8 bf1 = load_bf8(Wt + (size_t)(n0 + 16 + l16) * KK + k);
        acc0 = __builtin_amdgcn_mfma_f32_16x16x32_bf16(a, bf0, acc0, 0, 0, 0);
        acc1 = __builtin_amdgcn_mfma_f32_16x16x32_bf16(a, bf1, acc1, 0, 0, 0);
    }

    #pragma unroll
    for (int i = 0; i < 4; ++i) {
        red[w][kg * 4 + i][l16]      = acc0[i];
        red[w][kg * 4 + i][16 + l16] = acc1[i];
    }
    __syncthreads();

    const float* bias = is1 ? b1 : b2;
    for (int c = tid; c < 512; c += 256) {
        int m = c >> 5, n = c & 31;
        float s = red[0][m][n] + red[1][m][n] + red[2][m][n] + red[3][m][n];
        s = tanhf(s + bias[n0 + n]);
        int gi = (m0 + m) * N + (n0 + n);
        if (is1) {
            h1next[gi] = (__bf16)s;
            if (h1f32) h1f32[gi] = s;
        } else {
            h2next[gi] = (__bf16)s;
            if (h2f32) h2f32[gi] = s;
        }
    }
}

// out[64, V] = h2 @ emb_W^T + out_b.
__global__ __launch_bounds__(256) void proj_kernel(
    const __bf16* __restrict__ h2bf,
    const float* __restrict__ embW,
    const float* __restrict__ outb,
    float* __restrict__ out) {
    const int v0 = blockIdx.x << 6;
    const int tid = threadIdx.x;
    const int w = tid >> 6;
    const int l = tid & 63;
    const int l16 = l & 15, kg = l >> 4;
    const int vcol = v0 + w * 16 + l16;
    const int vr = vcol < VV ? vcol : VV - 1;
    f32x4 acc[4] = {{0,0,0,0},{0,0,0,0},{0,0,0,0},{0,0,0,0}};
    #pragma unroll 2
    for (int k0 = 0; k0 < EE; k0 += 32) {
        const int k = k0 + kg * 8;
        bf16x8 bfr = cvt8(embW + (size_t)vr * EE + k);
        #pragma unroll
        for (int mf = 0; mf < 4; ++mf) {
            bf16x8 a = load_bf8(h2bf + (mf * 16 + l16) * EE + k);
            acc[mf] = __builtin_amdgcn_mfma_f32_16x16x32_bf16(a, bfr, acc[mf], 0, 0, 0);
        }
    }
    if (vcol < VV) {
        const float bb = outb[vcol];
        #pragma unroll
        for (int mf = 0; mf < 4; ++mf) {
            #pragma unroll
            for (int i = 0; i < 4; ++i) {
                int b = mf * 16 + kg * 4 + i;
                out[(size_t)b * VV + vcol] = acc[mf][i] + bb;
            }
        }
    }
}

extern "C" void kernel_launch(void* const* d_in, const int* in_sizes, int n_in,
                              void* d_out, int out_size, void* d_ws, size_t ws_size,
                              hipStream_t stream) {
    const void* seq      = d_in[0];
    const float* init_h1 = (const float*)d_in[1];
    const float* init_h2 = (const float*)d_in[2];
    const float* embW    = (const float*)d_in[3];
    const float* W1      = (const float*)d_in[4];
    const float* b1      = (const float*)d_in[5];
    const float* W2      = (const float*)d_in[6];
    const float* b2      = (const float*)d_in[7];
    const float* outb    = (const float*)d_in[8];
    float* out = (float*)d_out;

    char* ws = (char*)d_ws;
    int* tok = (int*)ws;                 ws += (size_t)BB * SS * 4;
    __bf16* W1t = (__bf16*)ws;           ws += (size_t)HH * KK * 2;
    __bf16* W2t = (__bf16*)ws;           ws += (size_t)EE * KK * 2;
    __bf16* h1r = (__bf16*)ws;           ws += (size_t)4 * BB * HH * 2;  // ring x4
    __bf16* h2r = (__bf16*)ws;           ws += (size_t)4 * BB * EE * 2;  // ring x4
    unsigned* bar = (unsigned*)ws;       ws += 512;

    hipLaunchKernelGGL(tokens_kernel, dim3(128), dim3(256), 0, stream, seq, tok, bar);
    hipLaunchKernelGGL(transpose_kernel, dim3((KK / 32) * (HH / 32)), dim3(256), 0, stream,
                       W1, W1t, KK, HH);
    hipLaunchKernelGGL(transpose_kernel, dim3((KK / 32) * (EE / 32)), dim3(256), 0, stream,
                       W2, W2t, KK, EE);
    // init states into ring slot 0
    hipLaunchKernelGGL(init_kernel, dim3(256), dim3(256), 0, stream,
                       init_h1, init_h2, h1r, h2r);

    float* h1out = out + (size_t)BB * VV;
    float* h2out = h1out + (size_t)BB * HH;

    const int* tok_c = tok;
    const __bf16* W1t_c = W1t;
    const __bf16* W2t_c = W2t;
    void* args[] = {
        (void*)&tok_c, (void*)&embW, (void*)&b1, (void*)&b2,
        (void*)&W1t_c, (void*)&W2t_c,
        (void*)&h1r, (void*)&h2r,
        (void*)&h1out, (void*)&h2out, (void*)&bar
    };
    hipError_t err = hipLaunchCooperativeKernel((void*)rnn_persist2, dim3(NWG), dim3(256),
                                                args, 0, stream);
    if (err != hipSuccess) {
        // Deterministic fallback: proven per-step path (round 1), using ring
        // slots 0/1 as the two parity buffers. Final h2 lands in slot 0.
        __bf16* h1bf[2] = {h1r, h1r + (size_t)BB * HH};
        __bf16* h2bf[2] = {h2r, h2r + (size_t)BB * EE};
        for (int t = 0; t <= SS; ++t) {
            int g1 = (t < SS) ? 1 : 0;
            int g2 = (t >= 1) ? 1 : 0;
            const __bf16* h1cur = h1bf[t & 1];
            __bf16* h1next      = h1bf[(t + 1) & 1];
            const __bf16* h2cur = h2bf[(t + 1) & 1];
            __bf16* h2next      = h2bf[t & 1];
            float* h1f = (t == SS - 1) ? h1out : nullptr;
            float* h2f = (t == SS) ? h2out : nullptr;
            hipLaunchKernelGGL(step_kernel, dim3(192), dim3(256), 0, stream,
                               tok, embW, b1, b2, W1t, W2t,
                               h1cur, h1next, h2cur, h2next, h1f, h2f, t, g1, g2);
        }
    }

    // h2_512 lives in ring slot 0 (512 % 4 == 0) on both paths.
    hipLaunchKernelGGL(proj_kernel, dim3((VV + 63) / 64), dim3(256), 0, stream,
                       h2r, embW, outb, out);
}